// Round 7
// baseline (5703.294 us; speedup 1.0000x reference)
//
#include <hip/hip_runtime.h>
#include <hip/hip_bf16.h>
#include <stdint.h>

// GatedGNN: B=256, N=80, D=1024, T=3
#define B_   256
#define N_   80
#define D_   1024
#define M_   (B_*N_)     // 20480 rows (b*80+node)
// Abuf row (bf16), SA_=8192: [a_hi(0:2048)|a_lo(2048:4096)|h_hi(4096:5120)|h_lo(5120:6144)|rh_hi(6144:7168)|rh_lo(7168:8192)]
#define SA_  8192
// W row (bf16), SW_=6144: [w_a_hi(0:2048)|w_a_lo(2048:4096)|w_u_hi(4096:5120)|w_u_lo(5120:6144)]
#define SW_  6144
// Combined-plane staging at BK=32. 96 chunks: [0,64) a-part (K=2048), [64,96) u-part (K=1024).
#define KT_  96

typedef __attribute__((ext_vector_type(8))) short bf16x8;   // 8 bf16 = 4 VGPRs
typedef __attribute__((ext_vector_type(4))) float f32x4;

#define SB0() __builtin_amdgcn_sched_barrier(0)

__device__ __forceinline__ void async_cp16(const void* g, void* l) {
  __builtin_amdgcn_global_load_lds((const __attribute__((address_space(1))) unsigned int*)g,
                                   (__attribute__((address_space(3))) unsigned int*)l,
                                   16, 0, 0);
}
__device__ __forceinline__ float sigm_(float x) { return 1.0f / (1.0f + __expf(-x)); }
__device__ __forceinline__ float tanh_(float x) { return 2.0f / (1.0f + __expf(-2.0f * x)) - 1.0f; }
__device__ __forceinline__ void split_bf16(float v, __hip_bfloat16& hi, __hip_bfloat16& lo) {
  hi = __float2bfloat16(v);
  lo = __float2bfloat16(v - __bfloat162float(hi));
}
__device__ __forceinline__ void plane_offsets(int kt, int UBASE, int& ahi, int& alo, int& whi, int& wlo) {
  if (kt < 64) { const int c = kt * 32;        ahi = c;         alo = 2048 + c;
                 whi = c;                      wlo = 2048 + c; }
  else         { const int r = (kt - 64) * 32; ahi = UBASE + r; alo = UBASE + 1024 + r;
                 whi = 4096 + r;               wlo = 5120 + r; }
}

// ---------------- weight packing (hi/lo split): Wzr[2048][SW_], Wh[1024][SW_] ------------------
__global__ __launch_bounds__(256) void pack_weights(
    const float* __restrict__ W1w, const float* __restrict__ W1u,
    const float* __restrict__ W2w, const float* __restrict__ W2u,
    const float* __restrict__ W3w, const float* __restrict__ W3u,
    __hip_bfloat16* __restrict__ Wzr, __hip_bfloat16* __restrict__ Wh) {
  int idx = blockIdx.x * 256 + threadIdx.x;     // [0, 3072*3072)
  int n = idx / 3072, k = idx - n * 3072;       // n: 0..3071 output row, k: source col
  const float *Ww, *Wu; int nr; __hip_bfloat16* outrow;
  if (n < 1024)      { Ww = W1w; Wu = W1u; nr = n;        outrow = Wzr + (size_t)n * SW_; }
  else if (n < 2048) { Ww = W2w; Wu = W2u; nr = n - 1024; outrow = Wzr + (size_t)n * SW_; }
  else               { Ww = W3w; Wu = W3u; nr = n - 2048; outrow = Wh + (size_t)(n - 2048) * SW_; }
  float v; int chi, clo;
  if (k < 2048) { v = Ww[nr * 2048 + k];          chi = k;               clo = 2048 + k; }
  else          { v = Wu[nr * 1024 + (k - 2048)]; chi = 4096 + (k-2048); clo = 5120 + (k - 2048); }
  __hip_bfloat16 hi, lo; split_bf16(v, hi, lo);
  outrow[chi] = hi; outrow[clo] = lo;
}

// ---------------- propagation: a_in/a_out = inM/outM @ h[b] (fp32), split -> Abuf --------------
__global__ __launch_bounds__(256) void prop_kernel(
    const float* __restrict__ h, const float* __restrict__ inM,
    const float* __restrict__ outM, __hip_bfloat16* __restrict__ Abuf) {
  const int b = blockIdx.x;                        // chunk-local batch index
  const int d = blockIdx.y * 256 + threadIdx.x;
  const float* hb = h + (size_t)b * N_ * D_ + d;
  float hreg[N_];
  #pragma unroll
  for (int m = 0; m < N_; ++m) hreg[m] = hb[m * D_];
  __hip_bfloat16* Ab = Abuf + (size_t)b * N_ * SA_;
  #pragma unroll
  for (int m = 0; m < N_; ++m) {
    __hip_bfloat16 hi, lo; split_bf16(hreg[m], hi, lo);
    Ab[m * SA_ + 4096 + d] = hi; Ab[m * SA_ + 5120 + d] = lo;
  }
  for (int n = 0; n < N_; ++n) {
    float ai = 0.f, ao = 0.f;
    #pragma unroll
    for (int m = 0; m < N_; ++m) {
      ai += inM[n * N_ + m] * hreg[m];
      ao += outM[n * N_ + m] * hreg[m];
    }
    __hip_bfloat16 hi, lo;
    split_bf16(ai, hi, lo); Ab[n * SA_ + d] = hi;        Ab[n * SA_ + 2048 + d] = lo;
    split_bf16(ao, hi, lo); Ab[n * SA_ + 1024 + d] = hi; Ab[n * SA_ + 3072 + d] = lo;
  }
}

// ---------------- MFMA GEMM, 160x256 tile, BK=32 x 4 planes, 3-term split-bf16 ----------------
// R7: LDS-traffic reduction via bigger wave-tile (R4/R5/R6 post-mortem: both overlap styles sit
// on the LDS-pipe floor of 108 KB/block-iter; traffic-per-FLOP is set by geometry).
//   wave-grid 2x2, wave-tile 80m x 128n, acc 5x8 (160 regs). Block 160x256.
//   Per block-iter: 2x FLOPs of the old tile, LDS/feed only 1.44x -> -28% per FLOP.
//   A double-buffered half (40 KB, 5-load stage flies ~a full iter); B single-buffered (32 KB,
//   staged after the buffer-free barrier like R4). 72 KB LDS, 2 blocks/CU.
//   ZR: 1024 blocks = 2.0 exact rounds; H: 512 = 1.0 exact round (kills H's 1.33-round tail).
// All syncs are FULL drains (vmcnt(0)/lgkmcnt(0) + raw s_barrier) -- no fragile counting
// (R6 lesson: manual lgkm phasing fights the compiler and loses). bb_h is read per-ni inside
// the MFMA loop so it never fully materializes (register peak ~230 of 256 @ waves/EU=2).
// Ordering contract per iteration kt:
//   vmcnt(0)  -> A(kt) (half kt&1) and B(kt) landed;  s_barrier -> visible to all waves
//   STAGE_A(kt+1) -> half (kt+1)&1   [free: its readers drained before kt-1's 2nd barrier]
//   ds_read af_h/af_l; per-ni {bb_h read + seg0 + seg1}; ds_read bb_l[8]
//   lgkmcnt(0) -> all LDS reads retired;  s_barrier -> B buffer + A half free chip-wide
//   STAGE_B(kt+1)   [flies across seg2 + next iter's top]
//   seg2 per-ni
// MFMA order per acc element unchanged (hh, lh, hl) -> bit-identical numerics.
// Bank-conflict swizzle (R4, verified 0): slot q holds global chunk q^((row>>1)&3);
// swizzle term is invariant under row += 16, so +mi*64/+ni*64 indexing is unchanged.
template<bool IS_ZR>
__global__ __launch_bounds__(256, 2) void gemm_kernel(
    const __hip_bfloat16* __restrict__ Abuf,   // [rows][SA_] chunk-local
    const __hip_bfloat16* __restrict__ W,      // [Nout][SW_]
    const float* __restrict__ bw1, const float* __restrict__ bu1,
    const float* __restrict__ bw2, const float* __restrict__ bu2,
    const float* __restrict__ hcur,            // [rows][1024] fp32, chunk-local
    float* __restrict__ zbuf,                  // [rows][1024] fp32, chunk-local
    __hip_bfloat16* __restrict__ rhbase,       // = Abuf (rh at cols 6144/7168)
    float* __restrict__ hout,
    int mtiles) {
  __shared__ bf16x8 ldsA[2560];   // 40 KB: half(2) x plane(2) x 160 m-rows x 4 chunks
  __shared__ bf16x8 ldsB[2048];   // 32 KB: plane(2) x 256 n-rows x 4 chunks

  const int ntiles = IS_ZR ? 8 : 4;            // 256-wide n tiles
  int mt, nt;
  if ((mtiles & 7) == 0) {
    const int flat = blockIdx.x;
    const int strip = mtiles >> 3;             // m-tiles per XCD
    const int xcd = flat & 7;
    const int loc = flat >> 3;                 // [0, strip*ntiles)
    mt = xcd * strip + loc / ntiles;
    nt = loc - (loc / ntiles) * ntiles;
  } else {
    mt = blockIdx.x / ntiles;
    nt = blockIdx.x - mt * ntiles;
  }
  const int m0 = mt * 160;
  const int n0 = nt * 256;

  const int tid  = threadIdx.x;
  const int lane = tid & 63;
  const int wave = tid >> 6;
  const int wm   = (wave & 1) * 80;
  const int wn   = (wave >> 1) * 128;
  const int l15  = lane & 15;
  const int l4   = lane >> 4;
  const int UBASE = IS_ZR ? 4096 : 6144;   // u-operand: h for ZR, r*h for H

  f32x4 acc[5][8];
  #pragma unroll
  for (int i = 0; i < 5; ++i)
    #pragma unroll
    for (int j = 0; j < 8; ++j) acc[i][j] = (f32x4){0.f, 0.f, 0.f, 0.f};

  // swizzled, loop-invariant operand read offsets (slot units of 16B)
  const int arow = wm + l15;
  const int brow = wn + l15;
  const int aoff = arow * 4 + (l4 ^ ((arow >> 1) & 3));
  const int boff = brow * 4 + (l4 ^ ((brow >> 1) & 3));

  // A staging: 5 async 16B copies into half HF (slots: plane(2) x 160 x 4).
  #define STAGE_A(HF, AHI, ALO) do {                                                           \
      _Pragma("unroll")                                                                        \
      for (int i_ = 0; i_ < 5; ++i_) {                                                         \
        const int cidx = i_ * 256 + tid;                                                       \
        const int pl = cidx / 640;                                                             \
        const int rr = cidx - pl * 640;                                                        \
        const int q  = rr & 3;                                                                 \
        const int mm = rr >> 2;                                                                \
        const int qg = q ^ ((mm >> 1) & 3);                                                    \
        async_cp16(Abuf + (size_t)(m0 + mm) * SA_ + (pl ? (ALO) : (AHI)) + qg * 8,             \
                   &ldsA[(HF) * 1280 + cidx]);                                                 \
      }                                                                                        \
    } while (0)
  // B staging: 8 async 16B copies (slots: plane(2) x 256 x 4).
  #define STAGE_B(WHI, WLO) do {                                                               \
      _Pragma("unroll")                                                                        \
      for (int j_ = 0; j_ < 8; ++j_) {                                                         \
        const int cidx = j_ * 256 + tid;                                                       \
        const int pl = cidx >> 10;                                                             \
        const int rr = cidx & 1023;                                                           \
        const int q  = rr & 3;                                                                 \
        const int nn = rr >> 2;                                                                \
        const int qg = q ^ ((nn >> 1) & 3);                                                    \
        async_cp16(W + (size_t)(n0 + nn) * SW_ + (pl ? (WLO) : (WHI)) + qg * 8,                \
                   &ldsB[cidx]);                                                               \
      }                                                                                        \
    } while (0)

  // prologue: stage A(0) into half 0 and B(0)
  int ahi, alo, whi, wlo;
  plane_offsets(0, UBASE, ahi, alo, whi, wlo);
  STAGE_A(0, ahi, alo);
  STAGE_B(whi, wlo);

  for (int kt = 0; kt < KT_; ++kt) {
    asm volatile("s_waitcnt vmcnt(0)" ::: "memory");   // A(kt), B(kt) landed (this wave)
    SB0();
    __builtin_amdgcn_s_barrier();                      // ... and visible chip-wide
    SB0();

    // stage A(kt+1) into the other half: its readers drained before kt-1's 2nd barrier.
    // Flies for ~a full iteration (awaited at top of kt+1).
    if (kt + 1 < KT_) {
      plane_offsets(kt + 1, UBASE, ahi, alo, whi, wlo);
      STAGE_A((kt + 1) & 1, ahi, alo);
    }
    SB0();

    const int abase = (kt & 1) * 1280;
    bf16x8 af_h[5], af_l[5];
    #pragma unroll
    for (int mi = 0; mi < 5; ++mi) { af_h[mi] = ldsA[abase + aoff + mi * 64];
                                     af_l[mi] = ldsA[abase + 640 + aoff + mi * 64]; }
    // seg0 + seg1, bb_h read per-ni (never fully live; compiler schedules read->MFMA waits)
    #pragma unroll
    for (int ni = 0; ni < 8; ++ni) {
      const bf16x8 bh = ldsB[boff + ni * 64];
      #pragma unroll
      for (int mi = 0; mi < 5; ++mi)           // seg0: a_hi * w_hi
        acc[mi][ni] = __builtin_amdgcn_mfma_f32_16x16x32_bf16(af_h[mi], bh, acc[mi][ni], 0, 0, 0);
      #pragma unroll
      for (int mi = 0; mi < 5; ++mi)           // seg1: a_lo * w_hi
        acc[mi][ni] = __builtin_amdgcn_mfma_f32_16x16x32_bf16(af_l[mi], bh, acc[mi][ni], 0, 0, 0);
    }
    bf16x8 bl[8];
    #pragma unroll
    for (int ni = 0; ni < 8; ++ni) bl[ni] = ldsB[1024 + boff + ni * 64];

    asm volatile("s_waitcnt lgkmcnt(0)" ::: "memory"); // all LDS reads retired (wave-local)
    SB0();
    __builtin_amdgcn_s_barrier();                      // B buffer + A half free chip-wide
    SB0();

    if (kt + 1 < KT_) STAGE_B(whi, wlo);               // flies across seg2 + next top
    SB0();

    #pragma unroll
    for (int ni = 0; ni < 8; ++ni)             // seg2: a_hi * w_lo
      #pragma unroll
      for (int mi = 0; mi < 5; ++mi)
        acc[mi][ni] = __builtin_amdgcn_mfma_f32_16x16x32_bf16(af_h[mi], bl[ni], acc[mi][ni], 0, 0, 0);
  }
  #undef STAGE_A
  #undef STAGE_B

  // epilogue: C/D layout col = lane&15, row = (lane>>4)*4 + reg
  #pragma unroll
  for (int mi = 0; mi < 5; ++mi) {
    #pragma unroll
    for (int p = 0; p < 4; ++p) {
      const int m = m0 + wm + mi * 16 + l4 * 4 + p;
      #pragma unroll
      for (int ni = 0; ni < 8; ++ni) {
        const int n = n0 + wn + ni * 16 + l15;
        float v = acc[mi][ni][p];
        if (IS_ZR) {
          if (n < 1024) {
            zbuf[(size_t)m * 1024 + n] = sigm_(v + bw1[n] + bu1[n]);
          } else {
            const int nn2 = n - 1024;
            float r = sigm_(v + bw2[nn2] + bu2[nn2]);
            float rh = r * hcur[(size_t)m * 1024 + nn2];
            __hip_bfloat16 hi, lo; split_bf16(rh, hi, lo);
            rhbase[(size_t)m * SA_ + 6144 + nn2] = hi;
            rhbase[(size_t)m * SA_ + 7168 + nn2] = lo;
          }
        } else {
          float hc = tanh_(v + bw1[n] + bu1[n]);
          float z  = zbuf[(size_t)m * 1024 + n];
          float ho = hcur[(size_t)m * 1024 + n];
          hout[(size_t)m * 1024 + n] = (1.0f - z) * ho + z * hc;
        }
      }
    }
  }
}

extern "C" void kernel_launch(void* const* d_in, const int* in_sizes, int n_in,
                              void* d_out, int out_size, void* d_ws, size_t ws_size,
                              hipStream_t stream) {
  const float* x    = (const float*)d_in[0];
  const float* inM  = (const float*)d_in[1];
  const float* outM = (const float*)d_in[2];
  const float* W1w  = (const float*)d_in[3];
  const float* b1w  = (const float*)d_in[4];
  const float* W1u  = (const float*)d_in[5];
  const float* b1u  = (const float*)d_in[6];
  const float* W2w  = (const float*)d_in[7];
  const float* b2w  = (const float*)d_in[8];
  const float* W2u  = (const float*)d_in[9];
  const float* b2u  = (const float*)d_in[10];
  const float* W3w  = (const float*)d_in[11];
  const float* b3w  = (const float*)d_in[12];
  const float* W3u  = (const float*)d_in[13];
  const float* b3u  = (const float*)d_in[14];
  float* hout = (float*)d_out;   // h lives in d_out across timesteps

  char* ws = (char*)d_ws;
  __hip_bfloat16* Wzr = (__hip_bfloat16*)ws;                 // 2048*6144*2 = 25,165,824 B
  __hip_bfloat16* Wh  = (__hip_bfloat16*)(ws + 25165824);    // 1024*6144*2 = 12,582,912 B
  const size_t fixed = 37748736;
  // per-batch-element chunk cost: Abuf 80*SA_*2 + zbuf 80*1024*4 = 1,638,400 B
  int Rb = 256;                                              // batch elems per chunk (mult of 8)
  while (Rb > 8 && fixed + (size_t)Rb * 1638400ull > ws_size) Rb -= 8;
  float* zbuf = (float*)(ws + fixed);                        // Rb*80*1024*4
  __hip_bfloat16* Abuf = (__hip_bfloat16*)(ws + fixed + (size_t)Rb * 327680ull);

  pack_weights<<<(3072 * 3072) / 256, 256, 0, stream>>>(
      W1w, W1u, W2w, W2u, W3w, W3u, Wzr, Wh);

  for (int t = 0; t < 3; ++t) {
    const float* hsrc = (t == 0) ? x : (const float*)hout;
    for (int b0 = 0; b0 < B_; b0 += Rb) {
      const int nb = (B_ - b0 < Rb) ? (B_ - b0) : Rb;
      const int rows = N_ * nb;                  // 80*nb, nb mult of 8 -> /160 integral
      const int mtiles = rows / 160;
      const float* hc = hsrc + (size_t)b0 * N_ * D_;
      prop_kernel<<<dim3(nb, D_ / 256), 256, 0, stream>>>(hc, inM, outM, Abuf);
      gemm_kernel<true><<<mtiles * 8, 256, 0, stream>>>(
          Abuf, Wzr, b1w, b1u, b2w, b2u, hc, zbuf, Abuf, nullptr, mtiles);
      gemm_kernel<false><<<mtiles * 4, 256, 0, stream>>>(
          Abuf, Wh, b3w, b3u, nullptr, nullptr, hc, zbuf, nullptr,
          hout + (size_t)b0 * N_ * D_, mtiles);
    }
  }
}

// Round 8
// 3158.753 us; speedup vs baseline: 1.8056x; 1.8056x over previous
//
#include <hip/hip_runtime.h>
#include <hip/hip_bf16.h>
#include <stdint.h>

// GatedGNN: B=256, N=80, D=1024, T=3
#define B_   256
#define N_   80
#define D_   1024
#define M_   (B_*N_)     // 20480 rows (b*80+node)
// R8: f16 2-term plan. Abuf row (f16), SA2_=4096: [a_in(0:1024)|a_out(1024:2048)|h(2048:3072)|rh(3072:4096)]
#define SA2_ 4096
// W row (f16), SW_=6144: [wa_hi(0:2048)|wa_lo(2048:4096)|wu_hi(4096:5120)|wu_lo(5120:6144)]
#define SW_  6144
// BK=32 chunks: [0,64) a-part (K=2048), [64,96) u-part (K=1024).
#define KT_  96

typedef _Float16 half_t;
typedef __attribute__((ext_vector_type(8))) _Float16 f16x8;  // 8 f16 = 4 VGPRs
typedef __attribute__((ext_vector_type(4))) float f32x4;

__device__ __forceinline__ void async_cp16(const void* g, void* l) {
  __builtin_amdgcn_global_load_lds((const __attribute__((address_space(1))) unsigned int*)g,
                                   (__attribute__((address_space(3))) unsigned int*)l,
                                   16, 0, 0);
}
__device__ __forceinline__ float sigm_(float x) { return 1.0f / (1.0f + __expf(-x)); }
__device__ __forceinline__ float tanh_(float x) { return 2.0f / (1.0f + __expf(-2.0f * x)) - 1.0f; }
// f16 hi/lo split: hi+lo reconstructs v to ~22 mantissa bits.
__device__ __forceinline__ void split_f16(float v, half_t& hi, half_t& lo) {
  hi = (half_t)v;
  lo = (half_t)(v - (float)hi);
}

// A-plane column + W hi/lo columns for K-chunk kt.
__device__ __forceinline__ void plane_offsets(int kt, int UBASE, int& acol, int& whi, int& wlo) {
  if (kt < 64) { const int c = kt * 32;        acol = c;         whi = c;        wlo = 2048 + c; }
  else         { const int r = (kt - 64) * 32; acol = UBASE + r; whi = 4096 + r; wlo = 5120 + r; }
}

// ---------------- weight packing (f16 hi/lo split): Wzr[2048][SW_], Wh[1024][SW_] --------------
__global__ __launch_bounds__(256) void pack_weights(
    const float* __restrict__ W1w, const float* __restrict__ W1u,
    const float* __restrict__ W2w, const float* __restrict__ W2u,
    const float* __restrict__ W3w, const float* __restrict__ W3u,
    half_t* __restrict__ Wzr, half_t* __restrict__ Wh) {
  int idx = blockIdx.x * 256 + threadIdx.x;     // [0, 3072*3072)
  int n = idx / 3072, k = idx - n * 3072;       // n: 0..3071 output row, k: source col
  const float *Ww, *Wu; int nr; half_t* outrow;
  if (n < 1024)      { Ww = W1w; Wu = W1u; nr = n;        outrow = Wzr + (size_t)n * SW_; }
  else if (n < 2048) { Ww = W2w; Wu = W2u; nr = n - 1024; outrow = Wzr + (size_t)n * SW_; }
  else               { Ww = W3w; Wu = W3u; nr = n - 2048; outrow = Wh + (size_t)(n - 2048) * SW_; }
  float v; int chi, clo;
  if (k < 2048) { v = Ww[nr * 2048 + k];          chi = k;               clo = 2048 + k; }
  else          { v = Wu[nr * 1024 + (k - 2048)]; chi = 4096 + (k-2048); clo = 5120 + (k - 2048); }
  half_t hi, lo; split_f16(v, hi, lo);
  outrow[chi] = hi; outrow[clo] = lo;
}

// ---------------- propagation: a_in/a_out = inM/outM @ h[b] (fp32) -> single-f16 Abuf ----------
__global__ __launch_bounds__(256) void prop_kernel(
    const float* __restrict__ h, const float* __restrict__ inM,
    const float* __restrict__ outM, half_t* __restrict__ Abuf) {
  const int b = blockIdx.x;                        // chunk-local batch index
  const int d = blockIdx.y * 256 + threadIdx.x;
  const float* hb = h + (size_t)b * N_ * D_ + d;
  float hreg[N_];
  #pragma unroll
  for (int m = 0; m < N_; ++m) hreg[m] = hb[m * D_];
  half_t* Ab = Abuf + (size_t)b * N_ * SA2_;
  #pragma unroll
  for (int m = 0; m < N_; ++m) Ab[m * SA2_ + 2048 + d] = (half_t)hreg[m];
  for (int n = 0; n < N_; ++n) {
    float ai = 0.f, ao = 0.f;
    #pragma unroll
    for (int m = 0; m < N_; ++m) {
      ai += inM[n * N_ + m] * hreg[m];
      ao += outM[n * N_ + m] * hreg[m];
    }
    Ab[n * SA2_ + d]        = (half_t)ai;
    Ab[n * SA2_ + 1024 + d] = (half_t)ao;
  }
}

// ---------------- MFMA GEMM, 160x128 tile, BK=32, f16 2-term (a * w_hi + a * w_lo) ------------
// wave-grid 2x2, wave-tile 80m x 64n, acc 5x4 (80 AGPR). 26 KB LDS, 3 blocks/CU (R4-proven
// residency optimum). Structure = R4's verified loop (R5/R6/R7 alternatives all lost):
//   vmcnt(0); __syncthreads()  -> tile kt in LDS chip-wide
//   13 ds_reads (af x5, bbh x4, bbl x4) -> regs
//   __syncthreads()            -> buffer dead (no VMEM outstanding here, implicit vmcnt free)
//   STAGE(kt+1) into same buffer (7 async loads fly under the 40 MFMAs)
//   seg0: a*w_hi (20 MFMA); seg1: a*w_lo (20 MFMA)
// Precision: A is exact-split f16 (a_hi+a_lo staged? NO -- A single f16 plane; W split hi/lo;
// computed a*(wh+wl) drops only a's own f16 rounding residual a_lo*w: per-element <=
// |a||w|*2^-11, K=2048 random-sign sum ~1e-3 pre-activation -- well under the 0.0156 budget.
// vs R4: MFMA/wave 60->40 (-33%), LDS traffic 108->78 KB/iter (-28%), staged 36->26 KB (-28%).
// Bank-conflict swizzle (R4, verified 0): slot q holds global chunk q^((row>>1)&3); read
// offsets fold the same XOR (invariant under row+=16).
template<bool IS_ZR>
__global__ __launch_bounds__(256, 3) void gemm_kernel(
    const half_t* __restrict__ Abuf,           // [rows][SA2_] chunk-local
    const half_t* __restrict__ W,              // [Nout][SW_]
    const float* __restrict__ bw1, const float* __restrict__ bu1,
    const float* __restrict__ bw2, const float* __restrict__ bu2,
    const float* __restrict__ hcur,            // [rows][1024] fp32, chunk-local
    float* __restrict__ zbuf,                  // [rows][1024] fp32, chunk-local
    half_t* __restrict__ rhbase,               // = Abuf (rh at col 3072)
    float* __restrict__ hout,
    int mtiles) {
  __shared__ f16x8 ldsA[640];    // 10 KB: 160 m-rows x 4 chunks (single plane)
  __shared__ f16x8 ldsB[1024];   // 16 KB: plane(2) x 128 n-rows x 4 chunks

  const int ntiles = IS_ZR ? 16 : 8;           // 128-wide n tiles
  int mt, nt;
  if ((mtiles & 7) == 0) {
    const int flat = blockIdx.x;
    const int strip = mtiles >> 3;             // m-tiles per XCD
    const int xcd = flat & 7;
    const int loc = flat >> 3;                 // [0, strip*ntiles)
    mt = xcd * strip + loc / ntiles;
    nt = loc - (loc / ntiles) * ntiles;
  } else {
    mt = blockIdx.x / ntiles;
    nt = blockIdx.x - mt * ntiles;
  }
  const int m0 = mt * 160;
  const int n0 = nt * 128;

  const int tid  = threadIdx.x;
  const int lane = tid & 63;
  const int wave = tid >> 6;
  const int wm   = (wave & 1) * 80;
  const int wn   = (wave >> 1) * 64;
  const int l15  = lane & 15;
  const int l4   = lane >> 4;
  const int UBASE = IS_ZR ? 2048 : 3072;   // u-operand: h for ZR, r*h for H

  f32x4 acc[5][4];
  #pragma unroll
  for (int i = 0; i < 5; ++i)
    #pragma unroll
    for (int j = 0; j < 4; ++j) acc[i][j] = (f32x4){0.f, 0.f, 0.f, 0.f};

  // swizzled, loop-invariant operand read offsets (slot units of 16B)
  const int arow = wm + l15;
  const int brow = wn + l15;
  const int aoff = arow * 4 + (l4 ^ ((arow >> 1) & 3));
  const int boff = brow * 4 + (l4 ^ ((brow >> 1) & 3));

  // staging: A 640 slots = 2/thread + 1 extra for waves 0-1 (wave-uniform branch);
  // B 1024 slots = 4/thread. Global chunk pre-swizzled by q^((row>>1)&3); LDS dest linear.
  #define STAGE_TILE(ACOL, WHI, WLO) do {                                                      \
      _Pragma("unroll")                                                                        \
      for (int i_ = 0; i_ < 2; ++i_) {                                                         \
        const int cidx = i_ * 256 + tid;                                                       \
        const int q  = cidx & 3;                                                               \
        const int mm = cidx >> 2;                                                              \
        const int qg = q ^ ((mm >> 1) & 3);                                                    \
        async_cp16(Abuf + (size_t)(m0 + mm) * SA2_ + (ACOL) + qg * 8, &ldsA[cidx]);            \
      }                                                                                        \
      if (tid < 128) {                           /* waves 0,1 fully active: slots 512-639 */   \
        const int cidx = 512 + tid;                                                            \
        const int q  = cidx & 3;                                                               \
        const int mm = cidx >> 2;                                                              \
        const int qg = q ^ ((mm >> 1) & 3);                                                    \
        async_cp16(Abuf + (size_t)(m0 + mm) * SA2_ + (ACOL) + qg * 8, &ldsA[cidx]);            \
      }                                                                                        \
      _Pragma("unroll")                                                                        \
      for (int j_ = 0; j_ < 4; ++j_) {                                                         \
        const int cidx = j_ * 256 + tid;                                                       \
        const int pl = cidx >> 9;                                                              \
        const int q  = cidx & 3;                                                               \
        const int nn = (cidx >> 2) & 127;                                                      \
        const int qg = q ^ ((nn >> 1) & 3);                                                    \
        async_cp16(W + (size_t)(n0 + nn) * SW_ + (pl ? (WLO) : (WHI)) + qg * 8,                \
                   &ldsB[cidx]);                                                               \
      }                                                                                        \
    } while (0)

  // prologue: stage tile 0
  int acol, whi, wlo;
  plane_offsets(0, UBASE, acol, whi, wlo);
  STAGE_TILE(acol, whi, wlo);

  for (int kt = 0; kt < KT_; ++kt) {
    asm volatile("s_waitcnt vmcnt(0)" ::: "memory");   // this wave's stage writes landed
    __syncthreads();                                   // tile kt visible to all waves

    // read ALL operands to registers; the next barrier's lgkmcnt(0) drain completes them
    f16x8 af[5], bb_h[4], bb_l[4];
    #pragma unroll
    for (int mi = 0; mi < 5; ++mi) af[mi] = ldsA[aoff + mi * 64];
    #pragma unroll
    for (int ni = 0; ni < 4; ++ni) { bb_h[ni] = ldsB[boff + ni * 64];
                                     bb_l[ni] = ldsB[512 + boff + ni * 64]; }
    __syncthreads();                                   // all waves done with LDS -> reusable

    if (kt + 1 < KT_) {                                // stage kt+1 under the MFMAs below
      plane_offsets(kt + 1, UBASE, acol, whi, wlo);
      STAGE_TILE(acol, whi, wlo);
    }

    #pragma unroll
    for (int mi = 0; mi < 5; ++mi)             // seg0: a * w_hi
      #pragma unroll
      for (int ni = 0; ni < 4; ++ni)
        acc[mi][ni] = __builtin_amdgcn_mfma_f32_16x16x32_f16(af[mi], bb_h[ni], acc[mi][ni], 0, 0, 0);
    #pragma unroll
    for (int mi = 0; mi < 5; ++mi)             // seg1: a * w_lo
      #pragma unroll
      for (int ni = 0; ni < 4; ++ni)
        acc[mi][ni] = __builtin_amdgcn_mfma_f32_16x16x32_f16(af[mi], bb_l[ni], acc[mi][ni], 0, 0, 0);
  }
  #undef STAGE_TILE

  // epilogue: C/D layout col = lane&15, row = (lane>>4)*4 + reg
  #pragma unroll
  for (int mi = 0; mi < 5; ++mi) {
    #pragma unroll
    for (int p = 0; p < 4; ++p) {
      const int m = m0 + wm + mi * 16 + l4 * 4 + p;
      #pragma unroll
      for (int ni = 0; ni < 4; ++ni) {
        const int n = n0 + wn + ni * 16 + l15;
        float v = acc[mi][ni][p];
        if (IS_ZR) {
          if (n < 1024) {
            zbuf[(size_t)m * 1024 + n] = sigm_(v + bw1[n] + bu1[n]);
          } else {
            const int nn2 = n - 1024;
            float r = sigm_(v + bw2[nn2] + bu2[nn2]);
            float rh = r * hcur[(size_t)m * 1024 + nn2];
            rhbase[(size_t)m * SA2_ + 3072 + nn2] = (half_t)rh;
          }
        } else {
          float hc = tanh_(v + bw1[n] + bu1[n]);
          float z  = zbuf[(size_t)m * 1024 + n];
          float ho = hcur[(size_t)m * 1024 + n];
          hout[(size_t)m * 1024 + n] = (1.0f - z) * ho + z * hc;
        }
      }
    }
  }
}

extern "C" void kernel_launch(void* const* d_in, const int* in_sizes, int n_in,
                              void* d_out, int out_size, void* d_ws, size_t ws_size,
                              hipStream_t stream) {
  const float* x    = (const float*)d_in[0];
  const float* inM  = (const float*)d_in[1];
  const float* outM = (const float*)d_in[2];
  const float* W1w  = (const float*)d_in[3];
  const float* b1w  = (const float*)d_in[4];
  const float* W1u  = (const float*)d_in[5];
  const float* b1u  = (const float*)d_in[6];
  const float* W2w  = (const float*)d_in[7];
  const float* b2w  = (const float*)d_in[8];
  const float* W2u  = (const float*)d_in[9];
  const float* b2u  = (const float*)d_in[10];
  const float* W3w  = (const float*)d_in[11];
  const float* b3w  = (const float*)d_in[12];
  const float* W3u  = (const float*)d_in[13];
  const float* b3u  = (const float*)d_in[14];
  float* hout = (float*)d_out;   // h lives in d_out across timesteps

  char* ws = (char*)d_ws;
  half_t* Wzr = (half_t*)ws;                                 // 2048*6144*2 = 25,165,824 B
  half_t* Wh  = (half_t*)(ws + 25165824);                    // 1024*6144*2 = 12,582,912 B
  const size_t fixed = 37748736;
  // per-batch-element chunk cost: Abuf 80*SA2_*2 + zbuf 80*1024*4 = 983,040 B
  int Rb = 256;                                              // batch elems per chunk (mult of 8)
  while (Rb > 8 && fixed + (size_t)Rb * 983040ull > ws_size) Rb -= 8;
  float* zbuf = (float*)(ws + fixed);                        // Rb*80*1024*4
  half_t* Abuf = (half_t*)(ws + fixed + (size_t)Rb * 327680ull);

  pack_weights<<<(3072 * 3072) / 256, 256, 0, stream>>>(
      W1w, W1u, W2w, W2u, W3w, W3u, Wzr, Wh);

  for (int t = 0; t < 3; ++t) {
    const float* hsrc = (t == 0) ? x : (const float*)hout;
    for (int b0 = 0; b0 < B_; b0 += Rb) {
      const int nb = (B_ - b0 < Rb) ? (B_ - b0) : Rb;
      const int rows = N_ * nb;                  // 80*nb, nb mult of 8 -> /160 integral
      const int mtiles = rows / 160;
      const float* hc = hsrc + (size_t)b0 * N_ * D_;
      prop_kernel<<<dim3(nb, D_ / 256), 256, 0, stream>>>(hc, inM, outM, Abuf);
      gemm_kernel<true><<<mtiles * 16, 256, 0, stream>>>(
          Abuf, Wzr, b1w, b1u, b2w, b2u, hc, zbuf, Abuf, nullptr, mtiles);
      gemm_kernel<false><<<mtiles * 8, 256, 0, stream>>>(
          Abuf, Wh, b3w, b3u, nullptr, nullptr, hc, zbuf, nullptr,
          hout + (size_t)b0 * N_ * D_, mtiles);
    }
  }
}